// Round 3
// 88.095 us; speedup vs baseline: 1.0361x; 1.0361x over previous
//
#include <hip/hip_runtime.h>
#include <cstdint>

typedef float f32x4 __attribute__((ext_vector_type(4)));
typedef float f32x2 __attribute__((ext_vector_type(2)));
typedef __fp16 f16;
typedef f16 f16x2 __attribute__((ext_vector_type(2)));
typedef f16 f16x8 __attribute__((ext_vector_type(8)));

constexpr int Bv = 32;      // batch rows (M)
constexpr int Hv = 4096;    // hidden (K1, N2)
constexpr int Iv = 2048;    // intermediate
constexpr int N1 = 4096;    // 2*I

// ---------------------------------------------------------------------------
// fp4 e2m1 word (8 nibbles, LSB-first along K) -> 8 exact f16 values in
// PERMUTED fragment order: (n0,n2),(n4,n6),(n1,n3),(n5,n7).
// Legal because MFMA contracts A(q,j) with B(q,j): any within-lane j->k
// permutation is fine as long as A uses the SAME order (packA/k_swiglu do).
// f16 magnitude high-byte LUT (idx 0-7): 00,38,3C,3E,40,42,44,46; low byte 0.
// ---------------------------------------------------------------------------
__device__ __forceinline__ f16x8 dec8h(uint32_t w) {
  uint32_t lo = w & 0x07070707u;          // mag idx n0,n2,n4,n6
  uint32_t hi = (w >> 4) & 0x07070707u;   // mag idx n1,n3,n5,n7
  uint32_t e = __builtin_amdgcn_perm(0x46444240u, 0x3E3C3800u, lo)
             | ((w & 0x08080808u) << 4);  // high bytes + sign (even nibbles)
  uint32_t o = __builtin_amdgcn_perm(0x46444240u, 0x3E3C3800u, hi)
             | (w & 0x80808080u);         // high bytes + sign (odd nibbles)
  union { uint32_t u[4]; f16x8 v; } r;
  // zero-interleave: second perm source is 0 -> selector bytes 0x00 give 0x00
  r.u[0] = __builtin_amdgcn_perm(e, 0u, 0x05000400u);  // f16(n0), f16(n2)
  r.u[1] = __builtin_amdgcn_perm(e, 0u, 0x07000600u);  // f16(n4), f16(n6)
  r.u[2] = __builtin_amdgcn_perm(o, 0u, 0x05000400u);  // f16(n1), f16(n3)
  r.u[3] = __builtin_amdgcn_perm(o, 0u, 0x07000600u);  // f16(n5), f16(n7)
  return r.v;
}

// 8 consecutive f32 (originally fp16 -> exact) -> f16x8 in the same permuted
// fragment order (k-offsets 0,2,4,6,1,3,5,7).
__device__ __forceinline__ f16x8 packA(const float* p) {
  f32x4 a = *(const f32x4*)p;
  f32x4 b = *(const f32x4*)(p + 4);
  union { f16x2 h[4]; f16x8 v; } r;
  r.h[0] = __builtin_amdgcn_cvt_pkrtz(a[0], a[2]);
  r.h[1] = __builtin_amdgcn_cvt_pkrtz(b[0], b[2]);
  r.h[2] = __builtin_amdgcn_cvt_pkrtz(a[1], a[3]);
  r.h[3] = __builtin_amdgcn_cvt_pkrtz(b[1], b[3]);
  return r.v;
}

// ---------------------------------------------------------------------------
// K1: hp[kh][32][4096] = x @ dequant(W_gu)  (f32 partials)
// 256 wgs x 1024 thr (1 wg/CU): wg = 32-col tile x K-half. 16 waves = one
// 128-wide scale group each. f16 MFMA path: A exact (x was fp16), B exact
// (fp4 LUT values are exact f16); scale applied in f32 post-MFMA -> exact.
// Half the MFMA count of the old fp8 hi/lo scheme, no quantization VALU.
// ---------------------------------------------------------------------------
__global__ __launch_bounds__(1024, 4) void k_gateup(
    const float* __restrict__ x, const uint32_t* __restrict__ wp,
    const float* __restrict__ sc, float* __restrict__ hp) {
  __shared__ float lds[16 * 1024];
  const int nt = blockIdx.x >> 1;          // 0..127 (32-col tile)
  const int kh = blockIdx.x & 1;           // K half
  const int wid = threadIdx.x >> 6, lane = threadIdx.x & 63;
  const int q = lane >> 4, r = lane & 15;
  const int n0 = nt * 32;
  const int nA = n0 + r, nB = n0 + 16 + r;

  const int koff = kh * 2048 + wid * 128 + q * 8;    // elem offset in K
  const float* px0 = x + r * Hv + koff;
  const float* px1 = x + (r + 16) * Hv + koff;
  const uint32_t* pbA = wp + (size_t)(kh * 256 + wid * 16 + q) * N1 + nA;
  const uint32_t* pbB = pbA + 16;

  f32x4 t00 = {0,0,0,0}, t01 = {0,0,0,0}, t10 = {0,0,0,0}, t11 = {0,0,0,0};
  #pragma unroll
  for (int st = 0; st < 4; ++st) {         // 4 x K=32 steps = one group
    f16x8 A0 = packA(px0 + st * 32);
    f16x8 A1 = packA(px1 + st * 32);
    f16x8 BA = dec8h(pbA[(size_t)st * 4 * N1]);
    f16x8 BB = dec8h(pbB[(size_t)st * 4 * N1]);
    t00 = __builtin_amdgcn_mfma_f32_16x16x32_f16(A0, BA, t00, 0, 0, 0);
    t01 = __builtin_amdgcn_mfma_f32_16x16x32_f16(A0, BB, t01, 0, 0, 0);
    t10 = __builtin_amdgcn_mfma_f32_16x16x32_f16(A1, BA, t10, 0, 0, 0);
    t11 = __builtin_amdgcn_mfma_f32_16x16x32_f16(A1, BB, t11, 0, 0, 0);
  }
  const int g = kh * 16 + wid;             // this wave's scale group
  const float sA = sc[g * N1 + nA];
  const float sB = sc[g * N1 + nB];
  float* my = lds + wid * 1024;
  #pragma unroll
  for (int j = 0; j < 4; ++j) {
    const int rw = q * 4 + j;
    my[rw * 32 + r]             = sA * t00[j];
    my[rw * 32 + 16 + r]        = sB * t01[j];
    my[(16 + rw) * 32 + r]      = sA * t10[j];
    my[(16 + rw) * 32 + 16 + r] = sB * t11[j];
  }
  __syncthreads();
  const int i = threadIdx.x;               // 1024 outputs (32x32)
  float sum = 0.f;
  #pragma unroll
  for (int w = 0; w < 16; ++w) sum += lds[w * 1024 + i];
  hp[(size_t)kh * (Bv * N1) + (i >> 5) * N1 + n0 + (i & 31)] = sum;
}

// ---------------------------------------------------------------------------
// K2: SwiGLU over 2 f32 partial planes -> ONE f16 act plane [32,2048],
// stored in the permuted 8-group fragment order K3's MFMA expects.
// 128 wgs x 64 thr, 8 elems/thread, 16B stores.
// ---------------------------------------------------------------------------
__global__ __launch_bounds__(64) void k_swiglu(const float* __restrict__ hp,
                                               uint4* __restrict__ act) {
  const int t = blockIdx.x * 64 + threadIdx.x;  // 8192 threads
  const int m = t >> 8;
  const int c = (t & 255) * 8;
  constexpr int P = Bv * N1;
  const float* pg = hp + m * N1 + c;
  const float* pu = pg + Iv;
  f32x4 g0 = *(const f32x4*)pg       + *(const f32x4*)(pg + P);
  f32x4 g1 = *(const f32x4*)(pg + 4) + *(const f32x4*)(pg + 4 + P);
  f32x4 u0 = *(const f32x4*)pu       + *(const f32x4*)(pu + P);
  f32x4 u1 = *(const f32x4*)(pu + 4) + *(const f32x4*)(pu + 4 + P);
  float a[8];
  #pragma unroll
  for (int j = 0; j < 4; ++j) {
    float gv = g0[j];
    a[j] = gv / (1.0f + __expf(-gv)) * u0[j];
  }
  #pragma unroll
  for (int j = 0; j < 4; ++j) {
    float gv = g1[j];
    a[4 + j] = gv / (1.0f + __expf(-gv)) * u1[j];
  }
  union { f16x2 h[4]; uint4 u; } r;       // permuted order: 0,2 4,6 1,3 5,7
  r.h[0] = __builtin_amdgcn_cvt_pkrtz(a[0], a[2]);
  r.h[1] = __builtin_amdgcn_cvt_pkrtz(a[4], a[6]);
  r.h[2] = __builtin_amdgcn_cvt_pkrtz(a[1], a[3]);
  r.h[3] = __builtin_amdgcn_cvt_pkrtz(a[5], a[7]);
  act[t] = r.u;
}

// ---------------------------------------------------------------------------
// K3: out f32 [32][4096] = act[32,2048] @ dequant(W_down).
// 256 wgs x 1024 thr: wg = 16-col tile x full K(2048). f16 MFMA path:
// A = f16 act (16B loads, already fragment-ordered), B = exact f16 dequant.
// 8 MFMAs/wave (was 16 fp8).
// ---------------------------------------------------------------------------
__global__ __launch_bounds__(1024, 4) void k_down(
    const f16* __restrict__ act, const uint32_t* __restrict__ wp,
    const float* __restrict__ sc, float* __restrict__ out) {
  __shared__ float lds[16 * 512];
  const int n0 = blockIdx.x * 16;
  const int wid = threadIdx.x >> 6, lane = threadIdx.x & 63;
  const int q = lane >> 4, r = lane & 15;
  const int n = n0 + r;

  const int koff = wid * 128 + q * 8;
  const f16* pa0 = act + r * Iv + koff;
  const f16* pa1 = act + (r + 16) * Iv + koff;
  const uint32_t* pb = wp + (size_t)(wid * 16 + q) * Hv + n;

  f32x4 t0 = {0,0,0,0}, t1 = {0,0,0,0};
  #pragma unroll
  for (int st = 0; st < 4; ++st) {
    f16x8 A0 = *(const f16x8*)(pa0 + st * 32);
    f16x8 A1 = *(const f16x8*)(pa1 + st * 32);
    f16x8 B  = dec8h(pb[(size_t)st * 4 * Hv]);
    t0 = __builtin_amdgcn_mfma_f32_16x16x32_f16(A0, B, t0, 0, 0, 0);
    t1 = __builtin_amdgcn_mfma_f32_16x16x32_f16(A1, B, t1, 0, 0, 0);
  }
  const float sv = sc[wid * Hv + n];
  float* my = lds + wid * 512;
  #pragma unroll
  for (int j = 0; j < 4; ++j) {
    const int rw = q * 4 + j;
    my[rw * 16 + r]        = sv * t0[j];
    my[(16 + rw) * 16 + r] = sv * t1[j];
  }
  __syncthreads();
  const int i = threadIdx.x;
  if (i < 512) {                            // 512 outputs (32x16)
    float sum = 0.f;
    #pragma unroll
    for (int w = 0; w < 16; ++w) sum += lds[w * 512 + i];
    out[(i >> 4) * N1 + n0 + (i & 15)] = sum;
  }
}

// ---------------------------------------------------------------------------
extern "C" void kernel_launch(void* const* d_in, const int* in_sizes, int n_in,
                              void* d_out, int out_size, void* d_ws, size_t ws_size,
                              hipStream_t stream) {
  // Harness promotes float16 tensors to float32. x, scales, out are f32.
  const float*    x   = (const float*)d_in[0];      // f32 [32,4096]
  const uint32_t* gup = (const uint32_t*)d_in[1];   // [512,4096] packed fp4
  const float*    gus = (const float*)d_in[2];      // f32 [32,4096]
  const uint32_t* dnp = (const uint32_t*)d_in[3];   // [256,4096] packed fp4
  const float*    dns = (const float*)d_in[4];      // f32 [16,4096]

  float* hp  = (float*)d_ws;                        // [2][32][4096] f32 = 1 MiB
  f16*   act = (f16*)((char*)d_ws + 2 * (size_t)Bv * N1 * sizeof(float)); // 128 KiB

  k_gateup<<<256, 1024, 0, stream>>>(x, gup, gus, hp);
  k_swiglu<<<128,   64, 0, stream>>>(hp, (uint4*)act);
  k_down  <<<256, 1024, 0, stream>>>(act, dnp, dns, (float*)d_out);
}